// Round 5
// baseline (90.814 us; speedup 1.0000x reference)
//
#include <hip/hip_runtime.h>
#include <cstdint>
#include <cstddef>

#define N 8192
#define IN_F 256
#define OUT_F 128
#define ALPHA 0.2f
#define CAP 256
typedef unsigned long long ull;
typedef float f32x4 __attribute__((ext_vector_type(4)));

__device__ __forceinline__ float bf2f(unsigned short u) {
    return __uint_as_float(((unsigned)u) << 16);
}
__device__ __forceinline__ unsigned short f2bf(float f) {
    unsigned x = __float_as_uint(f);
    unsigned r = (x + 0x7FFFu + ((x >> 16) & 1u)) >> 16;   // round-nearest-even
    return (unsigned short)r;
}

// ---------------------------------------------------------------------------
// Kernel A (fused, heterogeneous blocks):
//   blockIdx <  256 : gemm  h = x@W (bf16 out) + fused s1,s2 epilogue.
//                     BK=32 -> LDS 21KB -> up to 7 blocks/CU co-residency.
//   blockIdx >= 256 : stream adj -> ballot bitmap (no atomics, NT loads).
// The VALU/LDS-bound gemm hides under the HBM-bound scan.
// ---------------------------------------------------------------------------
__global__ __launch_bounds__(256) void fused_gemm_scan(const float* __restrict__ x,
                                                       const float* __restrict__ W,
                                                       const float* __restrict__ a,
                                                       const float* __restrict__ adj,
                                                       unsigned short* __restrict__ hb,
                                                       float* __restrict__ s1,
                                                       float* __restrict__ s2,
                                                       ull* __restrict__ bm) {
    __shared__ __align__(16) float xsT[32 * 36];    // 4.6 KB [kk][r]
    __shared__ __align__(16) float ws2[32 * 128];   // 16 KB  [kk][o]
    const int tid = threadIdx.x;

    if (blockIdx.x < 256) {
        // ------------------------------ GEMM ------------------------------
        const int R0 = blockIdx.x * 32;
        const int r0 = (tid >> 5) * 4;
        const int c0 = (tid & 31) * 4;

        float acc[4][4];
#pragma unroll
        for (int r = 0; r < 4; ++r)
#pragma unroll
            for (int c = 0; c < 4; ++c) acc[r][c] = 0.f;

        for (int k0 = 0; k0 < IN_F; k0 += 32) {
            // stage x: 32 rows x 32 k = 256 float4, 1 per thread
            {
                const int r  = tid >> 3;
                const int k4 = tid & 7;
                const float4 v = *(const float4*)(x + (size_t)(R0 + r) * IN_F + k0 + k4 * 4);
                xsT[(k4 * 4 + 0) * 36 + r] = v.x;
                xsT[(k4 * 4 + 1) * 36 + r] = v.y;
                xsT[(k4 * 4 + 2) * 36 + r] = v.z;
                xsT[(k4 * 4 + 3) * 36 + r] = v.w;
            }
            // stage W: 32 k x 128 o = 1024 float4, 4 per thread
#pragma unroll
            for (int q = 0; q < 4; ++q) {
                const int f = tid + q * 256;
                *(float4*)(ws2 + f * 4) = *(const float4*)(W + (size_t)k0 * OUT_F + f * 4);
            }
            __syncthreads();

#pragma unroll 8
            for (int kk = 0; kk < 32; ++kk) {
                const float4 wv = *(const float4*)(ws2 + kk * 128 + c0);
                const float4 xv = *(const float4*)(xsT + kk * 36 + r0);
                acc[0][0] += xv.x * wv.x; acc[0][1] += xv.x * wv.y; acc[0][2] += xv.x * wv.z; acc[0][3] += xv.x * wv.w;
                acc[1][0] += xv.y * wv.x; acc[1][1] += xv.y * wv.y; acc[1][2] += xv.y * wv.z; acc[1][3] += xv.y * wv.w;
                acc[2][0] += xv.z * wv.x; acc[2][1] += xv.z * wv.y; acc[2][2] += xv.z * wv.z; acc[2][3] += xv.z * wv.w;
                acc[3][0] += xv.w * wv.x; acc[3][1] += xv.w * wv.y; acc[3][2] += xv.w * wv.z; acc[3][3] += xv.w * wv.w;
            }
            __syncthreads();
        }

#pragma unroll
        for (int r = 0; r < 4; ++r) {
            ushort4 o4;
            o4.x = f2bf(acc[r][0]); o4.y = f2bf(acc[r][1]);
            o4.z = f2bf(acc[r][2]); o4.w = f2bf(acc[r][3]);
            *(ushort4*)(hb + (size_t)(R0 + r0 + r) * OUT_F + c0) = o4;
        }

        const float4 a1v = *(const float4*)(a + c0);
        const float4 a2v = *(const float4*)(a + OUT_F + c0);
#pragma unroll
        for (int r = 0; r < 4; ++r) {
            float p1 = acc[r][0] * a1v.x + acc[r][1] * a1v.y + acc[r][2] * a1v.z + acc[r][3] * a1v.w;
            float p2 = acc[r][0] * a2v.x + acc[r][1] * a2v.y + acc[r][2] * a2v.z + acc[r][3] * a2v.w;
#pragma unroll
            for (int off = 16; off > 0; off >>= 1) {
                p1 += __shfl_xor(p1, off);
                p2 += __shfl_xor(p2, off);
            }
            if ((tid & 31) == 0) {
                s1[R0 + r0 + r] = p1;
                s2[R0 + r0 + r] = p2;
            }
        }
    } else {
        // ------------------------------ SCAN ------------------------------
        const int bid  = blockIdx.x - 256;
        const int lane = tid & 63;
        const size_t tg = (size_t)bid * 256 + tid;
        const f32x4* __restrict__ adj4 = (const f32x4*)adj;
#pragma unroll 8
        for (int it = 0; it < 32; ++it) {
            const size_t g = tg + (size_t)it * (2048u * 256u);
            const f32x4 v = __builtin_nontemporal_load(adj4 + g);
            const ull m0 = __ballot(v.x > 0.f);
            const ull m1 = __ballot(v.y > 0.f);
            const ull m2 = __ballot(v.z > 0.f);
            const ull m3 = __ballot(v.w > 0.f);
            if (lane < 4) {
                const ull mv = lane == 0 ? m0 : (lane == 1 ? m1 : (lane == 2 ? m2 : m3));
                __builtin_nontemporal_store(mv, bm + (g >> 6) * 4 + lane);
            }
        }
    }
}

// ---------------------------------------------------------------------------
// Kernel B: one wave per row. Decode bitmap -> LDS list (wave prefix scan),
// wave-parallel softmax, 2-entries-per-iteration bf16 gather, ELU.
// grid 2048 x 256 (4 waves = 4 rows per block).
// ---------------------------------------------------------------------------
__global__ __launch_bounds__(256, 8) void gat_gather(const ull* __restrict__ bm,
                                                     const unsigned short* __restrict__ hb,
                                                     const float* __restrict__ s1,
                                                     const float* __restrict__ s2,
                                                     float* __restrict__ out) {
    const int tid  = threadIdx.x;
    const int wv   = tid >> 6;
    const int lane = tid & 63;
    const int row  = blockIdx.x * 4 + wv;

    __shared__ int   jl[4][CAP];
    __shared__ float el[4][CAP];

    // ---- decode: lane owns bitmap words 2*lane, 2*lane+1 (16B coalesced)
    const ull* bmrow = bm + (size_t)row * 128;
    const ulonglong2 ww = *(const ulonglong2*)(bmrow + 2 * lane);
    const int cnt = __popcll(ww.x) + __popcll(ww.y);

    int scan = cnt;                       // inclusive prefix over lanes
#pragma unroll
    for (int d = 1; d < 64; d <<= 1) {
        const int y = __shfl_up(scan, d);
        if (lane >= d) scan += y;
    }
    const int total = __shfl(scan, 63);
    int p = scan - cnt;                   // exclusive offset
    {
        ull w = ww.x;
        const int wi = 2 * lane;
        const int base = (wi >> 2) * 256 + (wi & 3);
        while (w) {
            const int b = __builtin_ctzll(w);
            w &= w - 1;
            if (p < CAP) jl[wv][p] = base + 4 * b;
            ++p;
        }
    }
    {
        ull w = ww.y;
        const int wi = 2 * lane + 1;
        const int base = (wi >> 2) * 256 + (wi & 3);
        while (w) {
            const int b = __builtin_ctzll(w);
            w &= w - 1;
            if (p < CAP) jl[wv][p] = base + 4 * b;
            ++p;
        }
    }
    __syncthreads();
    const int n = total < CAP ? total : CAP;

    // ---- softmax over the list (<=4 entries per lane)
    const float si = s1[row];
    float ev[4];
    float lmax = -1e30f;
#pragma unroll
    for (int t = 0; t < 4; ++t) {
        const int l = lane + t * 64;
        float e = -1e30f;
        if (l < n) {
            e = si + s2[jl[wv][l]];
            e = e > 0.f ? e : ALPHA * e;
        }
        ev[t] = e;
        lmax = fmaxf(lmax, e);
    }
#pragma unroll
    for (int off = 32; off > 0; off >>= 1) lmax = fmaxf(lmax, __shfl_xor(lmax, off));

    float dp = 0.f;
#pragma unroll
    for (int t = 0; t < 4; ++t) {
        const int l = lane + t * 64;
        if (l < n) {
            const float wgt = __expf(ev[t] - lmax);
            el[wv][l] = wgt;
            dp += wgt;
        }
    }
#pragma unroll
    for (int off = 32; off > 0; off >>= 1) dp += __shfl_xor(dp, off);
    const float denom = dp;
    __syncthreads();

    // ---- gather: lane halves process even/odd entries; 32 lanes span 128 cols
    const int half = lane >> 5;
    const int col4 = (lane & 31) * 4;
    float a0 = 0.f, a1 = 0.f, a2 = 0.f, a3 = 0.f;
#pragma unroll 2
    for (int l = half; l < n; l += 2) {
        const float wgt = el[wv][l];
        const int j = jl[wv][l];
        const ushort4 hv = *(const ushort4*)(hb + (size_t)j * OUT_F + col4);
        a0 += wgt * bf2f(hv.x);
        a1 += wgt * bf2f(hv.y);
        a2 += wgt * bf2f(hv.z);
        a3 += wgt * bf2f(hv.w);
    }
    a0 += __shfl_xor(a0, 32);
    a1 += __shfl_xor(a1, 32);
    a2 += __shfl_xor(a2, 32);
    a3 += __shfl_xor(a3, 32);

    if (half == 0) {
        const float r = 1.f / denom;
        float v0 = a0 * r, v1 = a1 * r, v2 = a2 * r, v3 = a3 * r;
        float4 o;
        o.x = v0 > 0.f ? v0 : (__expf(v0) - 1.f);
        o.y = v1 > 0.f ? v1 : (__expf(v1) - 1.f);
        o.z = v2 > 0.f ? v2 : (__expf(v2) - 1.f);
        o.w = v3 > 0.f ? v3 : (__expf(v3) - 1.f);
        *(float4*)(out + (size_t)row * OUT_F + col4) = o;
    }
}

// ---------------------------------------------------------------------------
extern "C" void kernel_launch(void* const* d_in, const int* in_sizes, int n_in,
                              void* d_out, int out_size, void* d_ws, size_t ws_size,
                              hipStream_t stream) {
    const float* x   = (const float*)d_in[0];   // (8192, 256)
    const float* adj = (const float*)d_in[1];   // (8192, 8192)
    const float* W   = (const float*)d_in[2];   // (256, 128)
    const float* a   = (const float*)d_in[3];   // (256, 1)
    float* out = (float*)d_out;                 // (8192, 128) fp32

    char* wsb = (char*)d_ws;
    unsigned short* hb = (unsigned short*)wsb;                    // 2 MB bf16 h
    float* s1 = (float*)(wsb + 2 * 1024 * 1024);                  // 32 KB
    float* s2 = s1 + N;                                           // 32 KB
    ull*   bm = (ull*)(wsb + 2 * 1024 * 1024 + 64 * 1024);        // 8 MB bitmap

    fused_gemm_scan<<<256 + 2048, 256, 0, stream>>>(x, W, a, adj, hb, s1, s2, bm);
    gat_gather<<<2048, 256, 0, stream>>>(bm, hb, s1, s2, out);
}

// Round 6
// 71.093 us; speedup vs baseline: 1.2774x; 1.2774x over previous
//
#include <hip/hip_runtime.h>
#include <cstdint>
#include <cstddef>

#define N 8192
#define IN_F 256
#define OUT_F 128
#define ALPHA 0.2f
#define CAP 256
typedef unsigned long long ull;
typedef float f32x4 __attribute__((ext_vector_type(4)));

__device__ __forceinline__ float bf2f(unsigned short u) {
    return __uint_as_float(((unsigned)u) << 16);
}
__device__ __forceinline__ unsigned short f2bf(float f) {
    unsigned x = __float_as_uint(f);
    unsigned r = (x + 0x7FFFu + ((x >> 16) & 1u)) >> 16;   // round-nearest-even
    return (unsigned short)r;
}

// ---------------------------------------------------------------------------
// Kernel 1: h = x @ W (bf16 out), fused s1 = h.a1, s2 = h.a2 (fp32).
// grid 256 x 256 threads, BK=64, thread tile 4x4.  (R4 version, unchanged)
// ---------------------------------------------------------------------------
__global__ __launch_bounds__(256) void gemm_xw(const float* __restrict__ x,
                                               const float* __restrict__ W,
                                               const float* __restrict__ a,
                                               unsigned short* __restrict__ hb,
                                               float* __restrict__ s1,
                                               float* __restrict__ s2) {
    __shared__ __align__(16) float xsT[64 * 36];
    __shared__ __align__(16) float ws[64 * 128];
    const int tid = threadIdx.x;
    const int R0  = blockIdx.x * 32;
    const int r0  = (tid >> 5) * 4;
    const int c0  = (tid & 31) * 4;

    float acc[4][4];
#pragma unroll
    for (int r = 0; r < 4; ++r)
#pragma unroll
        for (int c = 0; c < 4; ++c) acc[r][c] = 0.f;

    for (int k0 = 0; k0 < IN_F; k0 += 64) {
#pragma unroll
        for (int q = 0; q < 2; ++q) {
            const int f  = tid + q * 256;
            const int r  = f >> 4;
            const int k4 = f & 15;
            const float4 v = *(const float4*)(x + (size_t)(R0 + r) * IN_F + k0 + k4 * 4);
            xsT[(k4 * 4 + 0) * 36 + r] = v.x;
            xsT[(k4 * 4 + 1) * 36 + r] = v.y;
            xsT[(k4 * 4 + 2) * 36 + r] = v.z;
            xsT[(k4 * 4 + 3) * 36 + r] = v.w;
        }
#pragma unroll
        for (int q = 0; q < 8; ++q) {
            const int f = tid + q * 256;
            *(float4*)(ws + f * 4) = *(const float4*)(W + (size_t)k0 * OUT_F + f * 4);
        }
        __syncthreads();

#pragma unroll 8
        for (int kk = 0; kk < 64; ++kk) {
            const float4 wv = *(const float4*)(ws + kk * 128 + c0);
            const float4 xv = *(const float4*)(xsT + kk * 36 + r0);
            acc[0][0] += xv.x * wv.x; acc[0][1] += xv.x * wv.y; acc[0][2] += xv.x * wv.z; acc[0][3] += xv.x * wv.w;
            acc[1][0] += xv.y * wv.x; acc[1][1] += xv.y * wv.y; acc[1][2] += xv.y * wv.z; acc[1][3] += xv.y * wv.w;
            acc[2][0] += xv.z * wv.x; acc[2][1] += xv.z * wv.y; acc[2][2] += xv.z * wv.z; acc[2][3] += xv.z * wv.w;
            acc[3][0] += xv.w * wv.x; acc[3][1] += xv.w * wv.y; acc[3][2] += xv.w * wv.z; acc[3][3] += xv.w * wv.w;
        }
        __syncthreads();
    }

#pragma unroll
    for (int r = 0; r < 4; ++r) {
        ushort4 o4;
        o4.x = f2bf(acc[r][0]); o4.y = f2bf(acc[r][1]);
        o4.z = f2bf(acc[r][2]); o4.w = f2bf(acc[r][3]);
        *(ushort4*)(hb + (size_t)(R0 + r0 + r) * OUT_F + c0) = o4;
    }

    const float4 a1v = *(const float4*)(a + c0);
    const float4 a2v = *(const float4*)(a + OUT_F + c0);
#pragma unroll
    for (int r = 0; r < 4; ++r) {
        float p1 = acc[r][0] * a1v.x + acc[r][1] * a1v.y + acc[r][2] * a1v.z + acc[r][3] * a1v.w;
        float p2 = acc[r][0] * a2v.x + acc[r][1] * a2v.y + acc[r][2] * a2v.z + acc[r][3] * a2v.w;
#pragma unroll
        for (int off = 16; off > 0; off >>= 1) {
            p1 += __shfl_xor(p1, off);
            p2 += __shfl_xor(p2, off);
        }
        if ((tid & 31) == 0) {
            s1[R0 + r0 + r] = p1;
            s2[R0 + r0 + r] = p2;
        }
    }
}

// ---------------------------------------------------------------------------
// Kernel 2: fully fused per-wave row processing. One wave = one row.
// No block barriers, no atomics, no bitmap roundtrip.
//   phase 1: stream row's 32KB of adj (software-pipelined float4 batches),
//            ballot-compact hit indices into per-wave LDS list (uniform
//            running counter in scalar regs).
//   phase 2: wave-parallel leaky-relu/max/exp/denom over the list.
//   phase 3: 2-way split bf16 gather of h, shfl combine, ELU, store.
// grid 2048 x 256 (4 waves = 4 rows / block).
// ---------------------------------------------------------------------------
__global__ __launch_bounds__(256, 8) void gat_fused(const float* __restrict__ adj,
                                                    const unsigned short* __restrict__ hb,
                                                    const float* __restrict__ s1,
                                                    const float* __restrict__ s2,
                                                    float* __restrict__ out) {
    const int tid  = threadIdx.x;
    const int wv   = tid >> 6;
    const int lane = tid & 63;
    const int row  = blockIdx.x * 4 + wv;

    __shared__ int   jl[4][CAP];
    __shared__ float el[4][CAP];

    const f32x4* __restrict__ arow = (const f32x4*)(adj + (size_t)row * N);
    const ull below = (1ull << lane) - 1ull;

    // ---- phase 1: scan 2048 float4 / 64 lanes = 32 per lane, batches of 4
    int tot = 0;
    f32x4 va[4], vb[4];
#pragma unroll
    for (int u = 0; u < 4; ++u) va[u] = arow[lane + u * 64];

    for (int b = 0; b < 8; ++b) {
        if (b < 7) {
#pragma unroll
            for (int u = 0; u < 4; ++u) vb[u] = arow[lane + ((b + 1) * 4 + u) * 64];
        }
#pragma unroll
        for (int u = 0; u < 4; ++u) {
            const int jb = ((b * 4 + u) * 64 + lane) * 4;
            const float av[4] = {va[u].x, va[u].y, va[u].z, va[u].w};
#pragma unroll
            for (int c = 0; c < 4; ++c) {
                const bool hit = av[c] > 0.f;
                const ull m = __ballot(hit);
                if (m) {                       // wave-uniform
                    const int base = tot;
                    tot += __popcll(m);
                    if (hit) {
                        const int p = base + __popcll(m & below);
                        if (p < CAP) jl[wv][p] = jb + c;
                    }
                }
            }
        }
#pragma unroll
        for (int u = 0; u < 4; ++u) va[u] = vb[u];
    }
    const int n = tot < CAP ? tot : CAP;

    // ---- phase 2: softmax over the list (<=4 entries per lane)
    const float si = s1[row];
    float ev[4];
    float lmax = -1e30f;
#pragma unroll
    for (int t = 0; t < 4; ++t) {
        const int l = lane + t * 64;
        float e = -1e30f;
        if (l < n) {
            e = si + s2[jl[wv][l]];
            e = e > 0.f ? e : ALPHA * e;
        }
        ev[t] = e;
        lmax = fmaxf(lmax, e);
    }
#pragma unroll
    for (int off = 32; off > 0; off >>= 1) lmax = fmaxf(lmax, __shfl_xor(lmax, off));

    float dp = 0.f;
#pragma unroll
    for (int t = 0; t < 4; ++t) {
        const int l = lane + t * 64;
        if (l < n) {
            const float wgt = __expf(ev[t] - lmax);
            el[wv][l] = wgt;
            dp += wgt;
        }
    }
#pragma unroll
    for (int off = 32; off > 0; off >>= 1) dp += __shfl_xor(dp, off);
    const float denom = dp;

    // ---- phase 3: gather; lane halves take even/odd entries, 32 lanes x 4 cols
    const int half = lane >> 5;
    const int col4 = (lane & 31) * 4;
    float a0 = 0.f, a1 = 0.f, a2 = 0.f, a3 = 0.f;
#pragma unroll 4
    for (int l = half; l < n; l += 2) {
        const float wgt = el[wv][l];
        const int j = jl[wv][l];
        const ushort4 hv = *(const ushort4*)(hb + (size_t)j * OUT_F + col4);
        a0 += wgt * bf2f(hv.x);
        a1 += wgt * bf2f(hv.y);
        a2 += wgt * bf2f(hv.z);
        a3 += wgt * bf2f(hv.w);
    }
    a0 += __shfl_xor(a0, 32);
    a1 += __shfl_xor(a1, 32);
    a2 += __shfl_xor(a2, 32);
    a3 += __shfl_xor(a3, 32);

    if (half == 0) {
        const float r = 1.f / denom;
        float v0 = a0 * r, v1 = a1 * r, v2 = a2 * r, v3 = a3 * r;
        float4 o;
        o.x = v0 > 0.f ? v0 : (__expf(v0) - 1.f);
        o.y = v1 > 0.f ? v1 : (__expf(v1) - 1.f);
        o.z = v2 > 0.f ? v2 : (__expf(v2) - 1.f);
        o.w = v3 > 0.f ? v3 : (__expf(v3) - 1.f);
        *(float4*)(out + (size_t)row * OUT_F + col4) = o;
    }
}

// ---------------------------------------------------------------------------
extern "C" void kernel_launch(void* const* d_in, const int* in_sizes, int n_in,
                              void* d_out, int out_size, void* d_ws, size_t ws_size,
                              hipStream_t stream) {
    const float* x   = (const float*)d_in[0];   // (8192, 256)
    const float* adj = (const float*)d_in[1];   // (8192, 8192)
    const float* W   = (const float*)d_in[2];   // (256, 128)
    const float* a   = (const float*)d_in[3];   // (256, 1)
    float* out = (float*)d_out;                 // (8192, 128) fp32

    char* wsb = (char*)d_ws;
    unsigned short* hb = (unsigned short*)wsb;                    // 2 MB bf16 h
    float* s1 = (float*)(wsb + 2 * 1024 * 1024);                  // 32 KB
    float* s2 = s1 + N;                                           // 32 KB

    gemm_xw<<<N / 32, 256, 0, stream>>>(x, W, a, hb, s1, s2);
    gat_fused<<<2048, 256, 0, stream>>>(adj, hb, s1, s2, out);
}